// Round 11
// baseline (319.930 us; speedup 1.0000x reference)
//
#include <hip/hip_runtime.h>

typedef _Float16 half_t;
typedef _Float16 v8h __attribute__((ext_vector_type(8)));
typedef _Float16 v4h __attribute__((ext_vector_type(4)));
typedef float v4f __attribute__((ext_vector_type(4)));

#define XTP 40   // xt LDS row pitch (halves): 32 data + 8 pad (16B-aligned rows)
#define HP  72   // h  LDS row pitch (halves): 64 data + 8 pad (16B-aligned rows)

typedef __attribute__((address_space(3))) unsigned int lds_u32;
typedef const __attribute__((address_space(1))) unsigned int glb_u32;

// async 16B/lane global->LDS DMA: lds dest = l + lane*16 (HW), src = g + lane*16
__device__ __forceinline__ void dma16(const half_t* g, half_t* l, int lane) {
  __builtin_amdgcn_global_load_lds((glb_u32*)(g + lane * 8), (lds_u32*)(l), 16, 0, 0);
}

// raw waitcnt: vmcnt(N), lgkmcnt/expcnt = no-wait (gfx9 encoding)
#define WAITVM(N) __builtin_amdgcn_s_waitcnt(0xF70 | (N))
#define SCHED0()  __builtin_amdgcn_sched_barrier(0)

// ===== W prep: W (128,K) f32 -> f16 chunked [K/8][128][8], load-coalesced =====
__global__ __launch_bounds__(256) void prep_w_all(const float* __restrict__ W0,
                                                  const float* __restrict__ W1,
                                                  const float* __restrict__ W2,
                                                  half_t* __restrict__ w0h,
                                                  half_t* __restrict__ w1h,
                                                  half_t* __restrict__ w2h) {
  int i = blockIdx.x * 256 + threadIdx.x;   // 0..81919
  const float* src; half_t* dst; int o, k8, ktot;
  if (i < 16384)      { o = i >> 7;               k8 = i & 127;      src = W0; dst = w0h; ktot = 1024; }
  else if (i < 49152) { int j = i - 16384; o = j >> 8; k8 = j & 255; src = W1; dst = w1h; ktot = 2048; }
  else                { int j = i - 49152; o = j >> 8; k8 = j & 255; src = W2; dst = w2h; ktot = 2048; }
  const float* s = src + (size_t)o * ktot + k8 * 8;   // consecutive lanes -> consecutive k8: coalesced
  float4 f0 = *(const float4*)s;
  float4 f1 = *(const float4*)(s + 4);
  union { half_t h[8]; uint4 u; } pk;
  pk.h[0] = (half_t)f0.x; pk.h[1] = (half_t)f0.y; pk.h[2] = (half_t)f0.z; pk.h[3] = (half_t)f0.w;
  pk.h[4] = (half_t)f1.x; pk.h[5] = (half_t)f1.y; pk.h[6] = (half_t)f1.z; pk.h[7] = (half_t)f1.w;
  *(uint4*)(dst + (size_t)(k8 * 128 + o) * 8) = pk.u;
}

// ===== one quad = 8 K32-steps of this wave's K-half; shared slab ring, vmcnt(2)+s_barrier =====
// ni-outer / mi-inner MFMA order: a[4] live (16 VGPR), bfr transient (4) -> fits 128 budget.
template <int G, int NSEL, bool TAIL>
__device__ __forceinline__ void quad8(const half_t* __restrict__ wbase, half_t* __restrict__ ring,
                                      int dmaofs, int sbase, int lane, int aoff,
                                      const half_t* __restrict__ xt_lds, int fofs, const int (&lrow)[4],
                                      const v8h (&hreg)[4][NSEL], v4f (&acc)[4][4]) {
  v8h xv8[4]; v4h xv4[4];
  if (G == 64) {
#pragma unroll
    for (int ni = 0; ni < 4; ++ni) xv4[ni] = *(const v4h*)(xt_lds + lrow[ni] * XTP + fofs + (sbase >> 1));
  } else {
#pragma unroll
    for (int ni = 0; ni < 4; ++ni) xv8[ni] = *(const v8h*)(xt_lds + lrow[ni] * XTP + fofs + sbase);
  }
#pragma unroll
  for (int i = 0; i < 8; ++i) {
    SCHED0();
    if (!TAIL || i <= 5) { WAITVM(2); } else if (i == 6) { WAITVM(1); } else { WAITVM(0); }
    __builtin_amdgcn_s_barrier();
    SCHED0();
    if (!TAIL || i <= 4)   // prefetch this wave's 1KB share of slab s+3
      dma16(wbase + (size_t)(sbase + i + 3) * 4096 + dmaofs,
            ring + ((i + 3) & 3) * 4096 + dmaofs, lane);
    const half_t* rb = ring + (i & 3) * 4096;   // sbase % 8 == 0 -> slot = i&3
    const int sel = (G == 64) ? (i & 1) : 0;
    v8h a[4];
#pragma unroll
    for (int mi = 0; mi < 4; ++mi) a[mi] = *(const v8h*)(rb + aoff + mi * 128);
#pragma unroll
    for (int ni = 0; ni < 4; ++ni) {
      half_t xs = (G == 64) ? xv4[ni][i >> 1] : xv8[ni][i];
      v8h bfr = hreg[ni][sel] * xs;             // Z fragment: x0[f,e]*h[g,e]
#pragma unroll
      for (int mi = 0; mi < 4; ++mi)
        acc[mi][ni] = __builtin_amdgcn_mfma_f32_16x16x32_f16(a[mi], bfr, acc[mi][ni], 0, 0, 0);
    }
  }
}

// ===== epilogue for ONE compile-time acc row (no dynamic register indexing!) =====
template <int MI, int KEEP, int OUT_BASE, bool H_OUT>
__device__ __forceinline__ void epi_row(v4f (&acc)[4][4], const float* __restrict__ bias,
                                        half_t* __restrict__ h_lds, float* __restrict__ out,
                                        size_t b0, int wm, int wb, int col, int kq) {
  const int o_base = wm + MI * 16 + kq * 4;
  float4 b4 = *(const float4*)(bias + o_base);
#pragma unroll
  for (int ni = 0; ni < 4; ++ni) {
    const int bb = wb + ni;
    float v[4];
#pragma unroll
    for (int r2 = 0; r2 < 4; ++r2)
      v[r2] = fmaxf(acc[MI][ni][r2] + (&b4.x)[r2], 0.0f);
    if (H_OUT && o_base >= 64) {          // effectively wave-uniform (thresholds are x16)
      union { half_t h[4]; uint2 u; } pk;
#pragma unroll
      for (int r2 = 0; r2 < 4; ++r2) pk.h[r2] = (half_t)v[r2];
      *(uint2*)(h_lds + (bb * 16 + col) * HP + (o_base - 64)) = pk.u;
    }
    if (o_base < KEEP) {                  // effectively wave-uniform
#pragma unroll
      for (int r2 = 0; r2 < 4; ++r2) {
        float sv = v[r2];
        sv += __shfl_xor(sv, 1);
        sv += __shfl_xor(sv, 2);
        sv += __shfl_xor(sv, 4);
        sv += __shfl_xor(sv, 8);          // sum over e (16-lane group)
        if (col == 0) out[(b0 + bb) * 256 + OUT_BASE + o_base + r2] = sv;
      }
    }
  }
}

// ============ one CIN layer (device). K-split-2: waves 0-7 K-half0, 8-15 K-half1. ============
// Wave tile 64(o) x 64(4 batch x 16 e); 8 tiles cover 128o x 256n (16 batch).
template <int G, int KTOT, int KEEP, int OUT_BASE, bool H_OUT, bool H_IS_X>
__device__ __forceinline__ void layer(const half_t* __restrict__ wgt,
                                      const float* __restrict__ bias,
                                      half_t* __restrict__ xt_lds,
                                      half_t* __restrict__ h_lds,
                                      half_t* __restrict__ w_ring,
                                      float* __restrict__ out,
                                      size_t b0, int tid) {
  constexpr int NSH = KTOT / 64;            // K32-steps per half (16 or 32)
  constexpr int NQ = NSH / 8;               // quads per half (2 or 4)
  constexpr int NSEL = (G == 64) ? 2 : 1;
  const int lane = tid & 63;
  const int wv = tid >> 6;                  // 0..15
  const int ks = wv >> 3;                   // K-half of this wave
  const int wq = wv & 7;
  const int wm = (wq & 1) * 64;             // o offset
  const int wb = (wq >> 1) * 4;             // local batch offset: 0,4,8,12
  const int col = lane & 15;                // = e
  const int kq = lane >> 4;                 // k-quad (fixed per lane)
  const int aoff = (kq * 128 + wm + col) * 8;
  const int fofs = ks * 16;                 // f-offset of this K-half (both G)
  const half_t* wbase = wgt + (size_t)ks * NSH * 4096;   // this half's slab stream
  half_t* ring = w_ring + ks * 16384;                    // 4 x 8KB slabs
  const int dmaofs = wq * 512;                           // this wave's 1KB share

  int lrow[4];
#pragma unroll
  for (int ni = 0; ni < 4; ++ni) lrow[ni] = (wb + ni) * 16 + col;

  __syncthreads();   // staging / prev layer h_lds visible; vmcnt fully drained

  const half_t* hb = H_IS_X ? xt_lds : h_lds;
  const int hpitch = H_IS_X ? XTP : HP;
  v8h hreg[4][NSEL];
#pragma unroll
  for (int ni = 0; ni < 4; ++ni) {
    const half_t* hp = hb + lrow[ni] * hpitch + kq * 8;
    hreg[ni][0] = *(const v8h*)hp;
    if (NSEL > 1) hreg[ni][NSEL - 1] = *(const v8h*)(hp + 32);
  }

  // prologue: this wave's share of slabs 0..2 of its half
#pragma unroll
  for (int p = 0; p < 3; ++p)
    dma16(wbase + (size_t)p * 4096 + dmaofs, ring + p * 4096 + dmaofs, lane);

  v4f acc[4][4] = {};
#pragma unroll 1
  for (int q = 0; q < NQ - 1; ++q)
    quad8<G, NSEL, false>(wbase, ring, dmaofs, q * 8, lane, aoff, xt_lds, fofs, lrow, hreg, acc);
  quad8<G, NSEL, true>(wbase, ring, dmaofs, (NQ - 1) * 8, lane, aoff, xt_lds, fofs, lrow, hreg, acc);

  // ---- K-split reduction via ring scratch (K-loop done; vmcnt 0; ring reusable) ----
  // stride 20 floats: 16B-aligned b128, per-wq region; all acc indices compile-time.
  float* scr = (float*)w_ring;
  float* my = scr + (wq * 64 + lane) * 20;
#pragma unroll
  for (int r = 0; r < 4; ++r) {             // r unrolled -> row/wks are constants
    constexpr int rowt[4] = {2, 3, 0, 1};
    const int row = rowt[r];
    const int wks = (r < 2) ? 0 : 1;        // writer half
    __syncthreads();
    if (ks == wks) {
      if (r == 0) { *(v4f*)(my) = acc[2][0]; *(v4f*)(my + 4) = acc[2][1]; *(v4f*)(my + 8) = acc[2][2]; *(v4f*)(my + 12) = acc[2][3]; }
      if (r == 1) { *(v4f*)(my) = acc[3][0]; *(v4f*)(my + 4) = acc[3][1]; *(v4f*)(my + 8) = acc[3][2]; *(v4f*)(my + 12) = acc[3][3]; }
      if (r == 2) { *(v4f*)(my) = acc[0][0]; *(v4f*)(my + 4) = acc[0][1]; *(v4f*)(my + 8) = acc[0][2]; *(v4f*)(my + 12) = acc[0][3]; }
      if (r == 3) { *(v4f*)(my) = acc[1][0]; *(v4f*)(my + 4) = acc[1][1]; *(v4f*)(my + 8) = acc[1][2]; *(v4f*)(my + 12) = acc[1][3]; }
    }
    __syncthreads();
    if (ks != wks) {
      if (r == 0) { acc[2][0] += *(const v4f*)(my); acc[2][1] += *(const v4f*)(my + 4); acc[2][2] += *(const v4f*)(my + 8); acc[2][3] += *(const v4f*)(my + 12); }
      if (r == 1) { acc[3][0] += *(const v4f*)(my); acc[3][1] += *(const v4f*)(my + 4); acc[3][2] += *(const v4f*)(my + 8); acc[3][3] += *(const v4f*)(my + 12); }
      if (r == 2) { acc[0][0] += *(const v4f*)(my); acc[0][1] += *(const v4f*)(my + 4); acc[0][2] += *(const v4f*)(my + 8); acc[0][3] += *(const v4f*)(my + 12); }
      if (r == 3) { acc[1][0] += *(const v4f*)(my); acc[1][1] += *(const v4f*)(my + 4); acc[1][2] += *(const v4f*)(my + 8); acc[1][3] += *(const v4f*)(my + 12); }
    }
    (void)row;
  }
  // now: ks0 owns final acc rows 0,1 (o in [wm,wm+32)); ks1 owns rows 2,3 ([wm+32,wm+64))

  // ---- epilogue: wave-uniform branch, compile-time row indices ----
  if (ks == 0) {
    epi_row<0, KEEP, OUT_BASE, H_OUT>(acc, bias, h_lds, out, b0, wm, wb, col, kq);
    epi_row<1, KEEP, OUT_BASE, H_OUT>(acc, bias, h_lds, out, b0, wm, wb, col, kq);
  } else {
    epi_row<2, KEEP, OUT_BASE, H_OUT>(acc, bias, h_lds, out, b0, wm, wb, col, kq);
    epi_row<3, KEEP, OUT_BASE, H_OUT>(acc, bias, h_lds, out, b0, wm, wb, col, kq);
  }
}

// ============ fused CIN: all 3 layers, one block = 16 batch elements ============
// 1024 thr (16 waves), grid 256 -> 1 block/CU -> 4 waves/SIMD with m64n64 tiles (K-split-2).
// LDS: xt 20KB + h 36KB + ring 64KB = 120KB. VGPR must fit 128 (launch_bounds 1024,4).
__global__ __launch_bounds__(1024, 4) void cin_fused(const float* __restrict__ x,
                                                     const half_t* __restrict__ w0h,
                                                     const half_t* __restrict__ w1h,
                                                     const half_t* __restrict__ w2h,
                                                     const float* __restrict__ b0p,
                                                     const float* __restrict__ b1p,
                                                     const float* __restrict__ b2p,
                                                     float* __restrict__ out) {
  __shared__ __align__(16) half_t xt_lds[256 * XTP];
  __shared__ __align__(16) half_t h_lds[256 * HP];
  __shared__ __align__(16) half_t w_ring[32768];   // 2 halves x 4 slabs x 8KB = 64KB

  const int tid = threadIdx.x;
  const size_t b0 = (size_t)blockIdx.x * 16;

  // ---- stage xt from x f32 (b,f,e) -> LDS (b,e) rows x 32 f, f16 ----
#pragma unroll
  for (int i = 0; i < 2; ++i) {
    int idx = (i * 1024 + tid) * 4;
    float4 v = *(const float4*)(x + b0 * 512 + idx);
    int e = idx & 15, f = (idx >> 4) & 31, b = idx >> 9;
    half_t* d = xt_lds + (b * 16 + e) * XTP + f;
    d[0 * XTP] = (half_t)v.x;
    d[1 * XTP] = (half_t)v.y;
    d[2 * XTP] = (half_t)v.z;
    d[3 * XTP] = (half_t)v.w;
  }

  layer<32, 1024, 64, 0, true, true>(w0h, b0p, xt_lds, h_lds, w_ring, out, b0, tid);
  layer<64, 2048, 64, 64, true, false>(w1h, b1p, xt_lds, h_lds, w_ring, out, b0, tid);
  layer<64, 2048, 128, 128, false, false>(w2h, b2p, xt_lds, h_lds, w_ring, out, b0, tid);
}

extern "C" void kernel_launch(void* const* d_in, const int* in_sizes, int n_in,
                              void* d_out, int out_size, void* d_ws, size_t ws_size,
                              hipStream_t stream) {
  const float* x  = (const float*)d_in[0];
  const float* W0 = (const float*)d_in[1];
  const float* b0 = (const float*)d_in[2];
  const float* W1 = (const float*)d_in[3];
  const float* b1 = (const float*)d_in[4];
  const float* W2 = (const float*)d_in[5];
  const float* b2 = (const float*)d_in[6];
  float* out = (float*)d_out;
  char* ws = (char*)d_ws;

  half_t* w0h = (half_t*)(ws);                       // 256 KB
  half_t* w1h = (half_t*)(ws + (256u << 10));        // 512 KB
  half_t* w2h = (half_t*)(ws + (768u << 10));        // 512 KB

  prep_w_all<<<320, 256, 0, stream>>>(W0, W1, W2, w0h, w1h, w2h);
  cin_fused<<<256, 1024, 0, stream>>>(x, w0h, w1h, w2h, b0, b1, b2, out);
}

// Round 12
// 153.359 us; speedup vs baseline: 2.0862x; 2.0862x over previous
//
#include <hip/hip_runtime.h>

typedef _Float16 half_t;
typedef _Float16 v8h __attribute__((ext_vector_type(8)));
typedef _Float16 v4h __attribute__((ext_vector_type(4)));
typedef float v4f __attribute__((ext_vector_type(4)));

#define XTP 40   // xt LDS row pitch (halves): 32 data + 8 pad (16B-aligned rows)
#define HP  72   // h  LDS row pitch (halves): 64 data + 8 pad (16B-aligned rows)

typedef __attribute__((address_space(3))) unsigned int lds_u32;
typedef const __attribute__((address_space(1))) unsigned int glb_u32;

// async 16B/lane global->LDS DMA: lds dest = l + lane*16 (HW), src = g + lane*16
__device__ __forceinline__ void dma16(const half_t* g, half_t* l, int lane) {
  __builtin_amdgcn_global_load_lds((glb_u32*)(g + lane * 8), (lds_u32*)(l), 16, 0, 0);
}

// raw waitcnt: vmcnt(N), lgkmcnt/expcnt = no-wait (gfx9 encoding)
#define WAITVM(N) __builtin_amdgcn_s_waitcnt(0xF70 | (N))
#define SCHED0()  __builtin_amdgcn_sched_barrier(0)

// ===== W prep: W (128,K) f32 -> f16, PASS-ORDERED slab layout =====
// G=64: k=k8*8, f=k8>>3, grem=k8&7, sel=grem>>2, kl=grem&3, ks=f>>4, fw=f&15
//   slab = (ks*2+sel)*16 + fw ;  dst chunk = slab*512 + kl*128 + o  (chunk = 8 halves)
// G=32: f=k8>>2, kl=k8&3, ks=f>>4, fw=f&15 ; slab = ks*16+fw ; chunk likewise.
__global__ __launch_bounds__(256) void prep_w_all(const float* __restrict__ W0,
                                                  const float* __restrict__ W1,
                                                  const float* __restrict__ W2,
                                                  half_t* __restrict__ w0h,
                                                  half_t* __restrict__ w1h,
                                                  half_t* __restrict__ w2h) {
  int i = blockIdx.x * 256 + threadIdx.x;   // 0..81919
  const float* src; half_t* dst; int o, k8, ktot, slab, kl;
  if (i < 16384) {
    o = i >> 7; k8 = i & 127; src = W0; dst = w0h; ktot = 1024;
    int f = k8 >> 2; kl = k8 & 3;
    slab = (f >> 4) * 16 + (f & 15);
  } else if (i < 49152) {
    int j = i - 16384; o = j >> 8; k8 = j & 255; src = W1; dst = w1h; ktot = 2048;
    int f = k8 >> 3, grem = k8 & 7, sel = grem >> 2; kl = grem & 3;
    slab = ((f >> 4) * 2 + sel) * 16 + (f & 15);
  } else {
    int j = i - 49152; o = j >> 8; k8 = j & 255; src = W2; dst = w2h; ktot = 2048;
    int f = k8 >> 3, grem = k8 & 7, sel = grem >> 2; kl = grem & 3;
    slab = ((f >> 4) * 2 + sel) * 16 + (f & 15);
  }
  const float* s = src + (size_t)o * ktot + k8 * 8;   // consecutive lanes -> consecutive k8
  float4 f0 = *(const float4*)s;
  float4 f1 = *(const float4*)(s + 4);
  union { half_t h[8]; uint4 u; } pk;
  pk.h[0] = (half_t)f0.x; pk.h[1] = (half_t)f0.y; pk.h[2] = (half_t)f0.z; pk.h[3] = (half_t)f0.w;
  pk.h[4] = (half_t)f1.x; pk.h[5] = (half_t)f1.y; pk.h[6] = (half_t)f1.z; pk.h[7] = (half_t)f1.w;
  *(uint4*)(dst + (size_t)(slab * 512 + kl * 128 + o) * 8) = pk.u;
}

// ===== 4 K32-steps; shared 3-slot slab ring, depth-2, vmcnt(2)+s_barrier; slots compile-time =====
template <int S0, bool TAIL>
__device__ __forceinline__ void quad4(const half_t* __restrict__ pbase, half_t* __restrict__ ringh,
                                      int dmaofs, int lane, int aoff,
                                      const half_t* __restrict__ xt_lds, int fbase,
                                      const int (&lrow)[4], const v8h (&hreg)[4], v4f (&acc)[4][4]) {
  v4h xv[4];
#pragma unroll
  for (int ni = 0; ni < 4; ++ni)
    xv[ni] = *(const v4h*)(xt_lds + lrow[ni] * XTP + fbase + S0);
#pragma unroll
  for (int i = 0; i < 4; ++i) {
    SCHED0();
    if (!TAIL || i < 3) { WAITVM(2); } else { WAITVM(0); }
    __builtin_amdgcn_s_barrier();
    SCHED0();
    if (!TAIL || i <= 1) {   // prefetch slab s+2
      const half_t* wsrc = pbase + (size_t)(S0 + i + 2) * 4096 + dmaofs;
      half_t* wdst = ringh + ((S0 + i + 2) % 3) * 4096 + dmaofs;
      dma16(wsrc, wdst, lane);
      dma16(wsrc + 512, wdst + 512, lane);
    }
    const half_t* rb = ringh + ((S0 + i) % 3) * 4096;
    v8h a[4];
#pragma unroll
    for (int mi = 0; mi < 4; ++mi) a[mi] = *(const v8h*)(rb + aoff + mi * 128);
#pragma unroll
    for (int ni = 0; ni < 4; ++ni) {
      v8h bfr = hreg[ni] * xv[ni][i];             // Z fragment: x0[f,e]*h[g,e]
#pragma unroll
      for (int mi = 0; mi < 4; ++mi)
        acc[mi][ni] = __builtin_amdgcn_mfma_f32_16x16x32_f16(a[mi], bfr, acc[mi][ni], 0, 0, 0);
    }
  }
}

// ===== one pass = 16 K32-steps at fixed (ks, g-range); hreg[4] only (16 VGPR) =====
__device__ __forceinline__ void run_pass(const half_t* __restrict__ pbase, half_t* __restrict__ ringh,
                                         int dmaofs, int lane, int aoff, int kq,
                                         const half_t* __restrict__ hb, int hpitch, int selofs,
                                         const half_t* __restrict__ xt_lds, int fbase,
                                         const int (&lrow)[4], v4f (&acc)[4][4]) {
  v8h hreg[4];
#pragma unroll
  for (int ni = 0; ni < 4; ++ni)
    hreg[ni] = *(const v8h*)(hb + lrow[ni] * hpitch + selofs + kq * 8);
#pragma unroll
  for (int p = 0; p < 2; ++p) {   // prologue: slabs 0,1
    const half_t* wsrc = pbase + (size_t)p * 4096 + dmaofs;
    half_t* wdst = ringh + p * 4096 + dmaofs;
    dma16(wsrc, wdst, lane);
    dma16(wsrc + 512, wdst + 512, lane);
  }
  quad4<0, false>(pbase, ringh, dmaofs, lane, aoff, xt_lds, fbase, lrow, hreg, acc);
  quad4<4, false>(pbase, ringh, dmaofs, lane, aoff, xt_lds, fbase, lrow, hreg, acc);
  quad4<8, false>(pbase, ringh, dmaofs, lane, aoff, xt_lds, fbase, lrow, hreg, acc);
  quad4<12, true>(pbase, ringh, dmaofs, lane, aoff, xt_lds, fbase, lrow, hreg, acc);
}

// ===== epilogue for ONE compile-time acc row =====
template <int MI, int KEEP, int OUT_BASE, bool H_OUT>
__device__ __forceinline__ void epi_row(v4f (&acc)[4][4], const float* __restrict__ bias,
                                        half_t* __restrict__ h_lds, float* __restrict__ out,
                                        size_t b0, int wm, int wb, int col, int kq) {
  const int o_base = wm + MI * 16 + kq * 4;
  float4 b4 = *(const float4*)(bias + o_base);
#pragma unroll
  for (int ni = 0; ni < 4; ++ni) {
    const int bb = wb + ni;
    float v[4];
#pragma unroll
    for (int r2 = 0; r2 < 4; ++r2)
      v[r2] = fmaxf(acc[MI][ni][r2] + (&b4.x)[r2], 0.0f);
    if (H_OUT && o_base >= 64) {
      union { half_t h[4]; uint2 u; } pk;
#pragma unroll
      for (int r2 = 0; r2 < 4; ++r2) pk.h[r2] = (half_t)v[r2];
      *(uint2*)(h_lds + (bb * 16 + col) * HP + (o_base - 64)) = pk.u;
    }
    if (o_base < KEEP) {
#pragma unroll
      for (int r2 = 0; r2 < 4; ++r2) {
        float sv = v[r2];
        sv += __shfl_xor(sv, 1);
        sv += __shfl_xor(sv, 2);
        sv += __shfl_xor(sv, 4);
        sv += __shfl_xor(sv, 8);   // sum over e (16-lane group)
        if (col == 0) out[(b0 + bb) * 256 + OUT_BASE + o_base + r2] = sv;
      }
    }
  }
}

// ============ one CIN layer. K-split-2 + sel-pass split. Wave tile 64(o) x 64(4b x 16e). ============
// 8 waves: bit0 wm(0/64), bit1 nb(0/4 batch), bit2 ks(K-half).
template <int G, int KEEP, int OUT_BASE, bool H_OUT, bool H_IS_X>
__device__ __forceinline__ void layer(const half_t* __restrict__ wgt, const float* __restrict__ bias,
                                      half_t* __restrict__ xt_lds, half_t* __restrict__ h_lds,
                                      half_t* __restrict__ w_ring, float* __restrict__ out,
                                      size_t b0, int tid) {
  constexpr int NSEL = (G == 64) ? 2 : 1;
  const int lane = tid & 63;
  const int wv = tid >> 6;             // 0..7
  const int ks = wv >> 2;              // K-half
  const int wm = (wv & 1) * 64;        // o offset
  const int nb = ((wv >> 1) & 1) * 4;  // local batch offset
  const int col = lane & 15;           // = e
  const int kq = lane >> 4;            // k-quad
  const int aoff = (kq * 128 + wm + col) * 8;
  const int dmaofs = (wv & 3) * 1024;  // wave's 2KB share of the 8KB slab
  half_t* ringh = w_ring + ks * 12288; // 3 slots x 4096 halves per half
  const int fbase = ks * 16;           // f-range of this K-half

  int lrow[4];
#pragma unroll
  for (int ni = 0; ni < 4; ++ni) lrow[ni] = (nb + ni) * 16 + col;

  const half_t* hb = H_IS_X ? xt_lds : h_lds;
  const int hpitch = H_IS_X ? XTP : HP;

  v4f acc[4][4] = {};

  __syncthreads();   // staging / prev-layer h_lds + ring WAR + vmcnt drain
  run_pass(wgt + (size_t)(ks * NSEL) * 65536, ringh, dmaofs, lane, aoff, kq,
           hb, hpitch, 0, xt_lds, fbase, lrow, acc);
  if (NSEL == 2) {
    __syncthreads();   // ring WAR between passes
    run_pass(wgt + (size_t)(ks * 2 + 1) * 65536, ringh, dmaofs, lane, aoff, kq,
             hb, hpitch, 32, xt_lds, fbase, lrow, acc);
  }

  // ---- K-split reduction via ring scratch (vmcnt=0 after pass tail) ----
  float* scr = (float*)w_ring;
  float* my = scr + (wv & 3) * 2048 + lane * 4;   // slot-major: slot*256 floats, lane*16B
  __syncthreads();
  if (ks == 0) {
    *(v4f*)(my + 0 * 256) = acc[2][0]; *(v4f*)(my + 1 * 256) = acc[2][1];
    *(v4f*)(my + 2 * 256) = acc[2][2]; *(v4f*)(my + 3 * 256) = acc[2][3];
    *(v4f*)(my + 4 * 256) = acc[3][0]; *(v4f*)(my + 5 * 256) = acc[3][1];
    *(v4f*)(my + 6 * 256) = acc[3][2]; *(v4f*)(my + 7 * 256) = acc[3][3];
  }
  __syncthreads();
  if (ks == 1) {
    acc[2][0] += *(const v4f*)(my + 0 * 256); acc[2][1] += *(const v4f*)(my + 1 * 256);
    acc[2][2] += *(const v4f*)(my + 2 * 256); acc[2][3] += *(const v4f*)(my + 3 * 256);
    acc[3][0] += *(const v4f*)(my + 4 * 256); acc[3][1] += *(const v4f*)(my + 5 * 256);
    acc[3][2] += *(const v4f*)(my + 6 * 256); acc[3][3] += *(const v4f*)(my + 7 * 256);
  }
  __syncthreads();
  if (ks == 1) {
    *(v4f*)(my + 0 * 256) = acc[0][0]; *(v4f*)(my + 1 * 256) = acc[0][1];
    *(v4f*)(my + 2 * 256) = acc[0][2]; *(v4f*)(my + 3 * 256) = acc[0][3];
    *(v4f*)(my + 4 * 256) = acc[1][0]; *(v4f*)(my + 5 * 256) = acc[1][1];
    *(v4f*)(my + 6 * 256) = acc[1][2]; *(v4f*)(my + 7 * 256) = acc[1][3];
  }
  __syncthreads();
  if (ks == 0) {
    acc[0][0] += *(const v4f*)(my + 0 * 256); acc[0][1] += *(const v4f*)(my + 1 * 256);
    acc[0][2] += *(const v4f*)(my + 2 * 256); acc[0][3] += *(const v4f*)(my + 3 * 256);
    acc[1][0] += *(const v4f*)(my + 4 * 256); acc[1][1] += *(const v4f*)(my + 5 * 256);
    acc[1][2] += *(const v4f*)(my + 6 * 256); acc[1][3] += *(const v4f*)(my + 7 * 256);
  }

  // ---- epilogue: wave-uniform ks branch, compile-time rows ----
  if (ks == 0) {
    epi_row<0, KEEP, OUT_BASE, H_OUT>(acc, bias, h_lds, out, b0, wm, nb, col, kq);
    epi_row<1, KEEP, OUT_BASE, H_OUT>(acc, bias, h_lds, out, b0, wm, nb, col, kq);
  } else {
    epi_row<2, KEEP, OUT_BASE, H_OUT>(acc, bias, h_lds, out, b0, wm, nb, col, kq);
    epi_row<3, KEEP, OUT_BASE, H_OUT>(acc, bias, h_lds, out, b0, wm, nb, col, kq);
  }
}

// ============ fused CIN: 3 layers, one block = 8 batch; 512 thr, grid 512 -> 2 blocks/CU ============
// LDS: xt 10KB + h 18KB + ring 48KB = 76KB -> 152KB/CU. VGPR target <=128 (launch_bounds 512,4).
__global__ __launch_bounds__(512, 4) void cin_fused(const float* __restrict__ x,
                                                    const half_t* __restrict__ w0h,
                                                    const half_t* __restrict__ w1h,
                                                    const half_t* __restrict__ w2h,
                                                    const float* __restrict__ b0p,
                                                    const float* __restrict__ b1p,
                                                    const float* __restrict__ b2p,
                                                    float* __restrict__ out) {
  __shared__ __align__(16) half_t xt_lds[128 * XTP];
  __shared__ __align__(16) half_t h_lds[128 * HP];
  __shared__ __align__(16) half_t w_ring[24576];   // 2 halves x 3 slabs x 4096 halves = 48KB

  const int tid = threadIdx.x;
  const size_t b0 = (size_t)blockIdx.x * 8;

  // ---- stage xt from x f32 (b,f,e) -> LDS (b,e) rows x 32 f, f16 ----
#pragma unroll
  for (int i = 0; i < 2; ++i) {
    int idx = (i * 512 + tid) * 4;
    float4 v = *(const float4*)(x + b0 * 512 + idx);
    int e = idx & 15, f = (idx >> 4) & 31, b = idx >> 9;
    half_t* d = xt_lds + (b * 16 + e) * XTP + f;
    d[0 * XTP] = (half_t)v.x;
    d[1 * XTP] = (half_t)v.y;
    d[2 * XTP] = (half_t)v.z;
    d[3 * XTP] = (half_t)v.w;
  }

  layer<32, 64, 0, true, true>(w0h, b0p, xt_lds, h_lds, w_ring, out, b0, tid);
  layer<64, 64, 64, true, false>(w1h, b1p, xt_lds, h_lds, w_ring, out, b0, tid);
  layer<64, 128, 128, false, false>(w2h, b2p, xt_lds, h_lds, w_ring, out, b0, tid);
}

extern "C" void kernel_launch(void* const* d_in, const int* in_sizes, int n_in,
                              void* d_out, int out_size, void* d_ws, size_t ws_size,
                              hipStream_t stream) {
  const float* x  = (const float*)d_in[0];
  const float* W0 = (const float*)d_in[1];
  const float* b0 = (const float*)d_in[2];
  const float* W1 = (const float*)d_in[3];
  const float* b1 = (const float*)d_in[4];
  const float* W2 = (const float*)d_in[5];
  const float* b2 = (const float*)d_in[6];
  float* out = (float*)d_out;
  char* ws = (char*)d_ws;

  half_t* w0h = (half_t*)(ws);                       // 256 KB
  half_t* w1h = (half_t*)(ws + (256u << 10));        // 512 KB
  half_t* w2h = (half_t*)(ws + (768u << 10));        // 512 KB

  prep_w_all<<<320, 256, 0, stream>>>(W0, W1, W2, w0h, w1h, w2h);
  cin_fused<<<512, 512, 0, stream>>>(x, w0h, w1h, w2h, b0, b1, b2, out);
}